// Round 12
// baseline (155.326 us; speedup 1.0000x reference)
//
#include <hip/hip_runtime.h>
#include <math.h>

typedef __attribute__((ext_vector_type(2))) float f32x2;
typedef __attribute__((ext_vector_type(4))) float fx4;
typedef __attribute__((ext_vector_type(8))) short s16x8;

// ================= zero fill =================

__global__ void zero_k(int4* __restrict__ p, int n4){
  int i = blockIdx.x*blockDim.x + threadIdx.x;
  if(i < n4) p[i] = make_int4(0,0,0,0);
}

// ================= CSR scans / fill (SUBK=1: 50k domain) =================

__global__ void scan1_k(const int* __restrict__ cnt, int* __restrict__ bsum, int n){
  __shared__ int ws[16];
  int i = blockIdx.x*1024 + threadIdx.x;
  int v = (i < n) ? cnt[i] : 0;
  #pragma unroll
  for(int m=1;m<64;m<<=1) v += __shfl_xor(v, m);
  if((threadIdx.x & 63) == 0) ws[threadIdx.x >> 6] = v;
  __syncthreads();
  if(threadIdx.x == 0){
    int s = 0;
    #pragma unroll
    for(int w=0; w<16; w++) s += ws[w];
    bsum[blockIdx.x] = s;
  }
}

__global__ __launch_bounds__(1024) void scan2_k(int* __restrict__ bsum, int nb,
                                                int* __restrict__ row_ptr, int n, int E){
  __shared__ int sm[1024];
  int t = threadIdx.x;
  int v = (t < nb) ? bsum[t] : 0;
  sm[t] = v;
  __syncthreads();
  for(int off=1; off<1024; off<<=1){
    int tv = (t>=off)? sm[t-off] : 0;
    __syncthreads();
    sm[t] += tv;
    __syncthreads();
  }
  if(t < nb) bsum[t] = sm[t] - v;
  if(t == 0) row_ptr[n] = E;
}

__global__ void scan3_k(const int* __restrict__ cnt, const int* __restrict__ bsum,
                        int* __restrict__ row_ptr, int n){
  __shared__ int sm[1024];
  int i = blockIdx.x*1024 + threadIdx.x;
  int v = (i<n)? cnt[i] : 0;
  sm[threadIdx.x] = v;
  __syncthreads();
  for(int off=1; off<1024; off<<=1){
    int t = (threadIdx.x>=off)? sm[threadIdx.x-off] : 0;
    __syncthreads();
    sm[threadIdx.x] += t;
    __syncthreads();
  }
  if(i<n)
    row_ptr[i] = sm[threadIdx.x] - v + bsum[blockIdx.x];
}

__global__ void fill2_k(const int* __restrict__ src, const int* __restrict__ dst,
                        const int* __restrict__ slot, const int* __restrict__ row_ptr,
                        int* __restrict__ csr_src, int E){
  int e = blockIdx.x*blockDim.x + threadIdx.x;
  if(e < E)
    csr_src[row_ptr[dst[e]] + slot[e]] = src[e];
}

// ================= bf16 helpers =================

__device__ __forceinline__ unsigned pack_bf2(float lo, float hi){
  unsigned ul = __float_as_uint(lo); ul += 0x7fffu + ((ul>>16)&1u);
  unsigned uh = __float_as_uint(hi); uh += 0x7fffu + ((uh>>16)&1u);
  return (uh & 0xffff0000u) | (ul >> 16);
}

// ================= shared GEMM core =================

__device__ __forceinline__ void gemm_core(uint4* Wl, const float* __restrict__ X,
    const float* __restrict__ b, unsigned short* __restrict__ Ybf, int nrows, int brow, int t)
{
  int wv = t >> 6, lane = t & 63;
  int r = lane & 15, kb = lane >> 4;
  int row = brow*64 + wv*16 + r;
  const float* xrow = &X[(size_t)min(row, nrows-1)*128];

  fx4 acc[8];
  #pragma unroll
  for(int c=0;c<8;c++) acc[c] = (fx4){0.f,0.f,0.f,0.f};

  #pragma unroll
  for(int kt=0;kt<4;kt++){
    int k0 = kt*32 + kb*8;
    float4 v0 = *(const float4*)&xrow[k0];
    float4 v1 = *(const float4*)&xrow[k0+4];
    float vs[8] = {v0.x,v0.y,v0.z,v0.w,v1.x,v1.y,v1.z,v1.w};
    s16x8 ahi, alo;
    #pragma unroll
    for(int j=0;j<8;j++){
      unsigned u = __float_as_uint(vs[j]);
      unsigned uh = u + 0x7fffu + ((u>>16)&1u);
      unsigned short h = (unsigned short)(uh >> 16);
      float hf = __uint_as_float(((unsigned)h)<<16);
      float lo = vs[j] - hf;
      unsigned ul = __float_as_uint(lo);
      ul += 0x7fffu + ((ul>>16)&1u);
      ahi[j] = (short)h;
      alo[j] = (short)(ul>>16);
    }
    int chunk = kt*4 + kb;
    #pragma unroll
    for(int c=0;c<8;c++){
      uint4 wb = Wl[((c*16 + r)<<4) | (chunk ^ r)];
      s16x8 bb = *(s16x8*)&wb;
      acc[c] = __builtin_amdgcn_mfma_f32_16x16x32_bf16(ahi, bb, acc[c], 0,0,0);
      acc[c] = __builtin_amdgcn_mfma_f32_16x16x32_bf16(alo, bb, acc[c], 0,0,0);
    }
  }

  __syncthreads();
  unsigned short* lds = (unsigned short*)Wl;
  unsigned short* my = lds + wv*2048;
  int colb = lane & 15;
  int rq0 = (lane>>4)*4;
  #pragma unroll
  for(int c=0;c<8;c++){
    int col = c*16 + colb;
    float bias = b[col];
    #pragma unroll
    for(int q=0;q<4;q++){
      unsigned u = __float_as_uint(acc[c][q] + bias);
      u += 0x7fffu + ((u>>16)&1u);
      my[(rq0+q)*128 + col] = (unsigned short)(u>>16);
    }
  }
  const uint4* my4 = (const uint4*)my;
  uint4* Y4 = (uint4*)Ybf;
  #pragma unroll
  for(int rr=0;rr<4;rr++){
    int idx = lane + 64*rr;
    int lrow = idx >> 4, lcol = idx & 15;
    int grow = brow*64 + wv*16 + lrow;
    if(grow < nrows)
      Y4[(size_t)grow*16 + lcol] = my4[idx];
  }
}

// ================= merged: gemm1 + countslot + W2 conv + fold =================

__global__ __launch_bounds__(256) void prep_gemm1_k(
    const float* __restrict__ X, const float* __restrict__ W1, const float* __restrict__ b1,
    unsigned short* __restrict__ XWbf, int nrows, int nGB,
    const int* __restrict__ dst, int* __restrict__ cnt, int* __restrict__ slot, int E, int nAB,
    const float* __restrict__ W2, unsigned short* __restrict__ W2bf,
    const float* __restrict__ Wp1, const float* __restrict__ bp1,
    const float* __restrict__ Wp2, const float* __restrict__ bp2,
    float* __restrict__ wfold)
{
  __shared__ uint4 Wl[128*16];
  int b = blockIdx.x;
  int t = threadIdx.x;

  if(b < nGB){
    #pragma unroll
    for(int i=0;i<8;i++){
      int idx = t + i*256;
      int row = idx >> 4, ch = idx & 15;
      const float* wsrc = &W1[(size_t)row*128 + ch*8];
      float4 va = *(const float4*)&wsrc[0];
      float4 vb = *(const float4*)&wsrc[4];
      uint4 o;
      o.x = pack_bf2(va.x, va.y); o.y = pack_bf2(va.z, va.w);
      o.z = pack_bf2(vb.x, vb.y); o.w = pack_bf2(vb.z, vb.w);
      Wl[(row<<4) | (ch ^ (row & 15))] = o;
    }
    __syncthreads();
    gemm_core(Wl, X, b1, XWbf, nrows, b, t);
    return;
  }
  int ab = b - nGB;
  if(ab < nAB){
    const int STR = nAB*256;
    int e = ab*256 + t;
    for(; e + 3*STR < E; e += 4*STR){
      int e1 = e+STR, e2 = e+2*STR, e3 = e+3*STR;
      int d0 = dst[e], d1 = dst[e1], d2 = dst[e2], d3 = dst[e3];
      int s0 = atomicAdd(&cnt[d0], 1);
      int s1 = atomicAdd(&cnt[d1], 1);
      int s2 = atomicAdd(&cnt[d2], 1);
      int s3 = atomicAdd(&cnt[d3], 1);
      slot[e] = s0; slot[e1] = s1; slot[e2] = s2; slot[e3] = s3;
    }
    for(; e < E; e += STR)
      slot[e] = atomicAdd(&cnt[dst[e]], 1);
    return;
  }
  int tb = ab - nAB;
  if(tb == 0){
    const float4* Ws = (const float4*)W2;
    uint2* Wd = (uint2*)W2bf;
    #pragma unroll
    for(int i=0;i<16;i++){
      int idx = t + i*256;
      float4 v = Ws[idx];
      uint2 o; o.x = pack_bf2(v.x, v.y); o.y = pack_bf2(v.z, v.w);
      Wd[idx] = o;
    }
    return;
  }
  int k = t;
  if(k < 128){
    float s = 0.f;
    for(int j=0;j<64;j++) s += Wp2[j]*Wp1[(size_t)j*128 + k];
    wfold[k] = s;
  } else if(k == 128){
    float s = bp2[0];
    for(int j=0;j<64;j++) s += Wp2[j]*bp1[j];
    wfold[128] = s;
  }
}

// ================= layer-2 GEMM =================

__global__ __launch_bounds__(256) void gemm_mfma_k(
    const float* __restrict__ X, const unsigned short* __restrict__ Wbf,
    const float* __restrict__ b, unsigned short* __restrict__ Ybf, int nrows)
{
  __shared__ uint4 Wl[128*16];
  int t = threadIdx.x;
  {
    const uint4* Ws = (const uint4*)Wbf;
    #pragma unroll
    for(int i=0;i<8;i++){
      int idx = t + i*256;
      int row = idx >> 4, ch = idx & 15;
      Wl[(row<<4) | (ch ^ (row & 15))] = Ws[idx];
    }
  }
  __syncthreads();
  gemm_core(Wl, X, b, Ybf, nrows, blockIdx.x, t);
}

// ================= GATv2 edge phase v6: 4 nodes/wave (group-per-node) =================
// 16-lane group g owns node (blk*16 + wid*4 + g); lane owns 8 channels (4 f32x2).
// 1 edge per group per iteration (4 row-gathers per wave-inst, same as v4), row+csr
// prefetched; loads exec-masked (no dup-gather), registers zero-init (no 0*garbage NaN).
// Prologue chain paid once per 4 nodes; no cross-group merges.

#define BFLO(u) __uint_as_float((u)<<16)
#define BFHI(u) __uint_as_float((u)&0xffff0000u)
#define DPP_ADD(v, ctrl) { int _t = __builtin_amdgcn_update_dpp(0, __float_as_int(v), ctrl, 0xF, 0xF, true); (v) += __int_as_float(_t); }

template<int FUSE>
__global__ __launch_bounds__(256) void gat_v6_k(
    const unsigned short* __restrict__ XWbf,
    const float* __restrict__ att,
    const int* __restrict__ row_ptr, const int* __restrict__ csr_src,
    float* __restrict__ outp, const float* __restrict__ wfold, int n)
{
  int wid = threadIdx.x >> 6, lane = threadIdx.x & 63;
  int g = lane >> 4;
  int cg = lane & 15;
  int c8 = cg * 8;
  int node = blockIdx.x*16 + wid*4 + g;
  bool nv = node < n;
  int nodec = nv ? node : (n-1);

  float4 A0 = *(const float4*)&att[c8];
  float4 A1 = *(const float4*)&att[c8+4];
  f32x2 a[4] = { {A0.x,A0.y}, {A0.z,A0.w}, {A1.x,A1.y}, {A1.z,A1.w} };

  const uint4* XW4 = (const uint4*)XWbf;
  uint4 du = XW4[(size_t)nodec*16 + cg];
  f32x2 xd[4] = { {BFLO(du.x),BFHI(du.x)}, {BFLO(du.y),BFHI(du.y)},
                  {BFLO(du.z),BFHI(du.z)}, {BFLO(du.w),BFHI(du.w)} };

  int beg = nv ? row_ptr[nodec]   : 0;
  int end = nv ? row_ptr[nodec+1] : 0;

  float s = 0.f;
  f32x2 acc[4] = {{0.f,0.f},{0.f,0.f},{0.f,0.f},{0.f,0.f}};

  int e = beg;
  int sn1 = 0;
  uint4 u = {0u,0u,0u,0u};
  if(e < end){
    int sn0 = csr_src[e];
    u = XW4[(size_t)sn0*16 + cg];
  }
  if(e+1 < end) sn1 = csr_src[e+1];

  while(__any(e < end)){
    bool ok  = e < end;
    bool okn = (e+1) < end;
    uint4 un = u;                                   // finite fallback
    if(okn) un = XW4[(size_t)sn1*16 + cg];          // row prefetch (masked)
    int sn2 = ((e+2) < end) ? csr_src[e+2] : sn1;   // csr prefetch

    f32x2 x0 = {BFLO(u.x), BFHI(u.x)};
    f32x2 x1 = {BFLO(u.y), BFHI(u.y)};
    f32x2 x2 = {BFLO(u.z), BFHI(u.z)};
    f32x2 x3 = {BFLO(u.w), BFHI(u.w)};
    f32x2 v0 = xd[0]+x0, v1 = xd[1]+x1, v2 = xd[2]+x2, v3 = xd[3]+x3;
    f32x2 q0 = v0*0.2f, q1 = v1*0.2f, q2 = v2*0.2f, q3 = v3*0.2f;
    f32x2 l0, l1, l2, l3;
    l0.x = fmaxf(v0.x,q0.x); l0.y = fmaxf(v0.y,q0.y);
    l1.x = fmaxf(v1.x,q1.x); l1.y = fmaxf(v1.y,q1.y);
    l2.x = fmaxf(v2.x,q2.x); l2.y = fmaxf(v2.y,q2.y);
    l3.x = fmaxf(v3.x,q3.x); l3.y = fmaxf(v3.y,q3.y);
    f32x2 p2 = l0*a[0];
    p2 += l1*a[1];
    p2 += l2*a[2];
    p2 += l3*a[3];
    float p = p2.x + p2.y;
    DPP_ADD(p, 0xB1);   // xor1
    DPP_ADD(p, 0x4E);   // xor2
    DPP_ADD(p, 0x141);  // half-mirror: 8-lane (per-head) sum complete
    float ex = ok ? __expf(fminf(p, 60.f)) : 0.f;
    s += ex;
    f32x2 e2 = {ex, ex};
    acc[0] += e2*x0;
    acc[1] += e2*x1;
    acc[2] += e2*x2;
    acc[3] += e2*x3;

    u = un; sn1 = sn2; e = e + 1;
  }

  float inv = (s > 0.f) ? 1.f/s : 0.f;
  f32x2 o[4];
  #pragma unroll
  for(int j=0;j<4;j++){
    o[j].x = fmaxf(acc[j].x*inv, 0.f);
    o[j].y = fmaxf(acc[j].y*inv, 0.f);
  }

  if(FUSE == 0){
    if(nv){
      *(float4*)&outp[(size_t)node*128 + c8]     = make_float4(o[0].x,o[0].y,o[1].x,o[1].y);
      *(float4*)&outp[(size_t)node*128 + c8 + 4] = make_float4(o[2].x,o[2].y,o[3].x,o[3].y);
    }
  } else {
    float4 wf0 = *(const float4*)&wfold[c8];
    float4 wf1 = *(const float4*)&wfold[c8+4];
    float tt = o[0].x*wf0.x + o[0].y*wf0.y + o[1].x*wf0.z + o[1].y*wf0.w
             + o[2].x*wf1.x + o[2].y*wf1.y + o[3].x*wf1.z + o[3].y*wf1.w;
    DPP_ADD(tt, 0xB1);
    DPP_ADD(tt, 0x4E);
    DPP_ADD(tt, 0x141);
    DPP_ADD(tt, 0x140);  // row-mirror: 16-lane (group) sum complete
    if(cg == 0 && nv)
      outp[node] = 1.f/(1.f + __expf(-(tt + wfold[128])));
  }
}

// ================= launcher =================

static inline size_t alignup(size_t v){ return (v + 255) & ~(size_t)255; }

extern "C" void kernel_launch(void* const* d_in, const int* in_sizes, int n_in,
                              void* d_out, int out_size, void* d_ws, size_t ws_size,
                              hipStream_t stream) {
  const float* x    = (const float*)d_in[0];
  const int*   ei   = (const int*)  d_in[1];
  const float* W1   = (const float*)d_in[2];
  const float* b1   = (const float*)d_in[3];
  const float* att1 = (const float*)d_in[4];
  const float* W2   = (const float*)d_in[5];
  const float* b2   = (const float*)d_in[6];
  const float* att2 = (const float*)d_in[7];
  const float* Wp1  = (const float*)d_in[8];
  const float* bp1  = (const float*)d_in[9];
  const float* Wp2  = (const float*)d_in[10];
  const float* bp2  = (const float*)d_in[11];
  float* out = (float*)d_out;

  int N = in_sizes[0] / 128;
  int E = in_sizes[1] / 2;

  char* ws = (char*)d_ws;
  size_t off = 0;
  float* G1            = (float*)(ws + off); off = alignup(off + (size_t)N*128*sizeof(float));
  unsigned short* XWbf = (unsigned short*)(ws + off); off = alignup(off + (size_t)N*128*sizeof(unsigned short));
  int* csr_src  = (int*)(ws + off); off = alignup(off + (size_t)E*sizeof(int));
  int* slot     = (int*)(ws + off); off = alignup(off + (size_t)E*sizeof(int));
  int* row_ptr  = (int*)(ws + off); off = alignup(off + (size_t)(N+1)*sizeof(int));
  int* cnt      = (int*)(ws + off); off = alignup(off + (size_t)(N+4)*sizeof(int));
  int* bsum     = (int*)(ws + off); off = alignup(off + 1024*sizeof(int));
  unsigned short* W2bf = (unsigned short*)(ws + off); off = alignup(off + 128*128*sizeof(unsigned short));
  float* wfold  = (float*)(ws + off); off = alignup(off + 129*sizeof(float));

  const int* esrc = ei;
  const int* edst = ei + E;

  int n4 = (N + 3) / 4;
  zero_k<<<(n4 + 255)/256, 256, 0, stream>>>((int4*)cnt, n4);

  int nGB = (N + 63) / 64;
  int nAB = 256;
  int nb = (N + 1023) / 1024;

  prep_gemm1_k<<<nGB + nAB + 2, 256, 0, stream>>>(
      x, W1, b1, XWbf, N, nGB,
      edst, cnt, slot, E, nAB,
      W2, W2bf, Wp1, bp1, Wp2, bp2, wfold);

  scan1_k<<<nb, 1024, 0, stream>>>(cnt, bsum, N);
  scan2_k<<<1, 1024, 0, stream>>>(bsum, nb, row_ptr, N, E);
  scan3_k<<<nb, 1024, 0, stream>>>(cnt, bsum, row_ptr, N);
  fill2_k<<<(E+255)/256, 256, 0, stream>>>(esrc, edst, slot, row_ptr, csr_src, E);

  int gatB = (N + 15) / 16;
  // layer 1 edge phase
  gat_v6_k<0><<<gatB, 256, 0, stream>>>(XWbf, att1, row_ptr, csr_src, G1, nullptr, N);
  // layer 2
  gemm_mfma_k<<<nGB, 256, 0, stream>>>(G1, W2bf, b2, XWbf, N);
  gat_v6_k<1><<<gatB, 256, 0, stream>>>(XWbf, att2, row_ptr, csr_src, out, wfold, N);
}